// Round 17
// baseline (152.237 us; speedup 1.0000x reference)
//
#include <hip/hip_runtime.h>
#include <math.h>

#define B_ 64
#define Q_ 50
#define N_ 32
#define E_ 64
#define D_ 128
#define H_ 4
#define EDIM_ 8
#define G_ (B_*Q_)

// d_ws layout (bytes)
#define WLP_OFF 0          // 4h x 4q x 128n x 32kk bf16 = 131072 B
#define WRP_OFF 131072
#define W1P_OFF 262144     // 4q x 128n x 32kk bf16 = 32768 B
#define W2P_OFF 294912
#define EW_OFF  327680     // 2 x 512 f32 = 4096 B  (emb_table @ We)

typedef __attribute__((ext_vector_type(8))) short short8;
typedef __attribute__((ext_vector_type(4))) float f32x4;
typedef __attribute__((ext_vector_type(4))) unsigned uint4e;
typedef __attribute__((ext_vector_type(2))) unsigned uint2e;
typedef __attribute__((ext_vector_type(2))) _Float16 half2e;
typedef __attribute__((ext_vector_type(2))) __fp16 fp16v2;
typedef unsigned short ushort_t;
typedef unsigned long long u64;

// f16/bf16 [32][128] LDS tile, XOR-swizzled at 16B granularity over 16 rows.
__device__ __forceinline__ int boff(int r, int d) {
  return (r << 7) + ((d & 0x78) ^ ((r & 15) << 3)) + (d & 7);
}

__device__ __forceinline__ ushort_t f2b(float f) {
  unsigned u = __float_as_uint(f);
  u += 0x7fffu + ((u >> 16) & 1u);
  return (ushort_t)(u >> 16);
}
__device__ __forceinline__ float b2f(ushort_t u) {
  return __uint_as_float(((unsigned)u) << 16);
}
// packed f32->bf16 (RNE), 2 elems / inst
__device__ __forceinline__ unsigned cvtpk(float lo, float hi) {
  unsigned r;
  asm("v_cvt_pk_bf16_f32 %0, %1, %2" : "=v"(r) : "v"(lo), "v"(hi));
  return r;
}
// packed f32->f16 (RTZ), 2 elems / inst, returns raw u32
__device__ __forceinline__ unsigned pkrtz(float lo, float hi) {
  union { fp16v2 h; unsigned u; } x;
  x.h = __builtin_amdgcn_cvt_pkrtz(lo, hi);
  return x.u;
}
__device__ __forceinline__ half2e u2h(unsigned u) {
  union { unsigned u; half2e h; } x; x.u = u; return x.h;
}
__device__ __forceinline__ float leakyf(float v, float s) {
  return fmaxf(v, s * v);   // valid for 0<s<1
}
// barrier that drains LDS only (keeps global loads in flight)
__device__ __forceinline__ void syncb() {
  asm volatile("s_waitcnt lgkmcnt(0)" ::: "memory");
  __builtin_amdgcn_s_barrier();
  asm volatile("" ::: "memory");
}

// ---------------- prep kernel: pack weights bf16 + EW = emb_table @ We ----------------
__global__ __launch_bounds__(256)
void pack_weights(const float* __restrict__ Wl, const float* __restrict__ Wr,
                  const float* __restrict__ W1, const float* __restrict__ W2,
                  const float* __restrict__ embT, const float* __restrict__ We,
                  unsigned char* __restrict__ ws)
{
  const int i = blockIdx.x * 256 + threadIdx.x;
  ushort_t* wlp = (ushort_t*)(ws + WLP_OFF);
  ushort_t* wrp = (ushort_t*)(ws + WRP_OFF);
  ushort_t* w1p = (ushort_t*)(ws + W1P_OFF);
  ushort_t* w2p = (ushort_t*)(ws + W2P_OFF);
  float* ew = (float*)(ws + EW_OFF);
  if (i < 65536) {
    // packed: idx = ((h*4+q)*128 + n)*32 + kk  <=  W[(q*32+kk)][h*128+n]
    const int kk = i & 31, n = (i >> 5) & 127, q = (i >> 12) & 3, h = i >> 14;
    wlp[i] = f2b(Wl[(q * 32 + kk) * (H_ * D_) + h * D_ + n]);
    wrp[i] = f2b(Wr[(q * 32 + kk) * (H_ * D_) + h * D_ + n]);
  } else if (i < 65536 + 16384) {
    const int j = i - 65536;
    const int kk = j & 31, n = (j >> 5) & 127, q = j >> 12;
    w1p[j] = f2b(W1[(q * 32 + kk) * D_ + n]);
    w2p[j] = f2b(W2[(q * 32 + kk) * D_ + n]);
  } else if (i < 65536 + 16384 + 1024) {
    const int j = i - 65536 - 16384;
    const int w = j >> 9, hd = j & 511;   // ew layout: [w][h*128+d]
    float a = 0.f;
#pragma unroll
    for (int k = 0; k < EDIM_; ++k) a = fmaf(embT[w * EDIM_ + k], We[k * (H_ * D_) + hd], a);
    ew[j] = a;
  }
}

// MFMA GEMM (swapped operands): [32 x 128] = A[32x128] @ W[128x128].
// F16OUT: write packed f16 (consumed by packed-math phases); else bf16 (next MFMA A-frag).
// LEAKY: apply leaky(slope) activation.
template <bool F16OUT, bool LEAKY>
__device__ __forceinline__ void gemm_e(const short8 aF[2][4], const ushort_t* __restrict__ Bp,
                                       const float* __restrict__ bias, float slope,
                                       ushort_t* __restrict__ dst, int lane, int nq)
{
#pragma unroll
  for (int nt = 0; nt < 2; ++nt) {
    const int colw = nq * 32 + nt * 16 + (lane & 15);
    const int oc0 = nq * 32 + nt * 16 + ((lane >> 4) << 2);
    const float4 bb = *(const float4*)&bias[oc0];
    f32x4 acc0 = {0.f, 0.f, 0.f, 0.f}, acc1 = {0.f, 0.f, 0.f, 0.f};
#pragma unroll
    for (int q = 0; q < 4; ++q) {
      const short8 b = *(const short8*)&Bp[((q << 7) + colw) * 32 + ((lane >> 4) << 3)];
      acc0 = __builtin_amdgcn_mfma_f32_16x16x32_bf16(b, aF[0][q], acc0, 0, 0, 0);
      acc1 = __builtin_amdgcn_mfma_f32_16x16x32_bf16(b, aF[1][q], acc1, 0, 0, 0);
    }
#pragma unroll
    for (int cc = 0; cc < 2; ++cc) {
      const f32x4 a = cc ? acc1 : acc0;
      const int node = cc * 16 + (lane & 15);
      float v0 = a[0] + bb.x, v1 = a[1] + bb.y, v2 = a[2] + bb.z, v3 = a[3] + bb.w;
      if (LEAKY) {
        v0 = leakyf(v0, slope); v1 = leakyf(v1, slope);
        v2 = leakyf(v2, slope); v3 = leakyf(v3, slope);
      }
      uint2e o;
      if (F16OUT) {
        o.x = pkrtz(v0, v1);
        o.y = pkrtz(v2, v3);
      } else {
        o.x = cvtpk(v0, v1);
        o.y = cvtpk(v2, v3);
      }
      *(uint2e*)&dst[boff(node, oc0)] = o;
    }
  }
}

// ---------------- main fused kernel: TWO groups per 512-thread block ----------------
__global__ __launch_bounds__(512, 4)
void gat_main(const unsigned char* __restrict__ ws,
              const float* __restrict__ qe,
              const float* __restrict__ ln1g, const float* __restrict__ ln1b,
              const int* __restrict__ qmask, const int* __restrict__ eidx,
              const int* __restrict__ ewt, const int* __restrict__ emsk,
              const float* __restrict__ bl, const float* __restrict__ br,
              const float* __restrict__ att, const float* __restrict__ gatb,
              const float* __restrict__ b1, const float* __restrict__ b2,
              const float* __restrict__ ln2g, const float* __restrict__ ln2b,
              float* __restrict__ out)
{
  const int t = threadIdx.x;
  const int grp = t >> 8;              // group within block (0/1)
  const int tg = t & 255;              // thread within group
  const int lane = t & 63;
  const int wv = (t >> 6) & 3;         // wave within group
  const int g = blockIdx.x * 2 + grp;

  // per-group LDS slices
  __shared__ __align__(16) ushort_t sX[2][N_ * D_];
  __shared__ __align__(16) ushort_t sXl[2][N_ * D_];
  __shared__ __align__(16) ushort_t sXr[2][N_ * D_];
  __shared__ u64 sInc[2][N_];
  __shared__ int sSrc[2][E_], sDst[2][E_], sWt[2][E_];
  __shared__ float sEm[2][E_], sNm[2][N_], sC0[2][N_], sC1[2][N_];
  __shared__ float sValid[2], sNmSum[2];

  // aliases into this group's sX region (live only between table-stage and gout)
  ushort_t* sXg  = sX[grp];
  ushort_t* sXlg = sXl[grp];
  ushort_t* sXrg = sXr[grp];
  ushort_t* sEW  = sXg;                      // [2][4][128] f16, elems 0..1023
  ushort_t* sAtt = sXg + 1024;               // [4][128] f16, elems 1024..1535
  float* sExpE = (float*)(sXg + 1536);       // 64 f32
  float* sExpS = (float*)(sXg + 1664);       // 32 f32
  float* sPool = (float*)(sXg + 1728);       // 128 f32 (post-FFN only)

  const ushort_t* wlp = (const ushort_t*)(ws + WLP_OFF);
  const ushort_t* wrp = (const ushort_t*)(ws + WRP_OFF);
  const ushort_t* w1p = (const ushort_t*)(ws + W1P_OFF);
  const ushort_t* w2p = (const ushort_t*)(ws + W2P_OFF);

  // ---- Phase A: LN1 -> bf16 swizzled LDS (nontemporal qe); stage edge data ----
  {
    const int r = tg >> 3, d0 = (tg & 7) << 4;
    const f32x4* src4 = (const f32x4*)(qe + ((size_t)g * N_ + r) * D_ + d0);
    f32x4 v4[4];
#pragma unroll
    for (int p = 0; p < 4; ++p) v4[p] = __builtin_nontemporal_load(src4 + p);
    const float* v = (const float*)v4;
    float s = 0.f, ss = 0.f;
#pragma unroll
    for (int i = 0; i < 16; ++i) { float x = v[i]; s += x; ss += x * x; }
#pragma unroll
    for (int m = 1; m < 8; m <<= 1) { s += __shfl_xor(s, m); ss += __shfl_xor(ss, m); }
    const float mu = s * (1.f / 128.f);
    const float inv = rsqrtf(ss * (1.f / 128.f) - mu * mu + 1e-5f);
    const f32x4* gg = (const f32x4*)&ln1g[d0];
    const f32x4* bb = (const f32x4*)&ln1b[d0];
    float o[16];
#pragma unroll
    for (int p = 0; p < 4; ++p) {
      const f32x4 g4 = gg[p], b4 = bb[p];
#pragma unroll
      for (int k = 0; k < 4; ++k)
        o[p * 4 + k] = (v[p * 4 + k] - mu) * inv * g4[k] + b4[k];
    }
    uint4e w0, w1;
    w0.x = cvtpk(o[0], o[1]);  w0.y = cvtpk(o[2], o[3]);
    w0.z = cvtpk(o[4], o[5]);  w0.w = cvtpk(o[6], o[7]);
    w1.x = cvtpk(o[8], o[9]);  w1.y = cvtpk(o[10], o[11]);
    w1.z = cvtpk(o[12], o[13]); w1.w = cvtpk(o[14], o[15]);
    *(uint4e*)&sXg[boff(r, d0)] = w0;
    *(uint4e*)&sXg[boff(r, d0 + 8)] = w1;
  }
  if (tg < E_) {
    sSrc[grp][tg] = eidx[(size_t)g * 2 * E_ + tg];
    sDst[grp][tg] = eidx[(size_t)g * 2 * E_ + E_ + tg];
    sWt[grp][tg] = ewt[(size_t)g * E_ + tg];
    sEm[grp][tg] = (float)emsk[(size_t)g * E_ + tg];
  } else if (tg < 96) {
    sNm[grp][tg - 64] = (float)qmask[(size_t)g * N_ + (tg - 64)];
  }
  syncb();

  // ---- A fragments (reused for all 8 E2 GEMMs) ----
  short8 aF[2][4];
#pragma unroll
  for (int c = 0; c < 2; ++c)
#pragma unroll
    for (int q = 0; q < 4; ++q)
      aF[c][q] = *(const short8*)&sXg[boff(c * 16 + (lane & 15), q * 32 + ((lane >> 4) << 3))];

  // ---- ballot-based per-node masks (wave wv owns nodes 8wv..8wv+7) ----
  {
    const int dl = sDst[grp][lane];
    const float eml = sEm[grp][lane];
    const int wtl = sWt[grp][lane];
    const bool val = eml > 0.f;
    const u64 wt0m = __ballot(wtl == 0);
#pragma unroll
    for (int k = 0; k < 8; ++k) {
      const int n = wv * 8 + k;
      const u64 inc = __ballot(val && dl == n);
      if (lane == k) {
        sInc[grp][n] = inc;
        const float cnt = (float)__popcll(inc);
        const float c0 = (float)__popcll(inc & wt0m);
        const float rinv = 1.f / fmaxf(cnt, 1.f);
        sC0[grp][n] = c0 * rinv;
        sC1[grp][n] = (cnt - c0) * rinv;
      }
    }
    if (wv == 3) {
      float nmv = (lane < 32) ? sNm[grp][lane] : 0.f;
      float emv = eml;
#pragma unroll
      for (int m = 1; m < 64; m <<= 1) { nmv += __shfl_xor(nmv, m); emv += __shfl_xor(emv, m); }
      if (lane == 0) {
        sNmSum[grp] = nmv;
        sValid[grp] = (nmv > 0.f && emv > 0.f) ? 1.f : 0.f;
      }
    }
  }
  syncb();   // all aF reads of sX done -> safe to overwrite sX region with tables

  // ---- stage EW / att tables (f16) into the (now dead) sX region ----
  {
    const float* ewg = (const float*)(ws + EW_OFF);
    const f32x4 e4 = *(const f32x4*)&ewg[tg << 2];
    uint2e p;
    p.x = pkrtz(e4[0], e4[1]);
    p.y = pkrtz(e4[2], e4[3]);
    *(uint2e*)&sEW[tg << 2] = p;
    if (tg < 128) {
      const f32x4 a4 = *(const f32x4*)&att[tg << 2];
      uint2e q;
      q.x = pkrtz(a4[0], a4[1]);
      q.y = pkrtz(a4[2], a4[3]);
      *(uint2e*)&sAtt[tg << 2] = q;
    }
  }

  const half2e pslope = {(_Float16)0.2f, (_Float16)0.2f};
  half2e accA[4] = {}, accB[4] = {};   // packed head-mean accum: node tg>>3, d = (tg&7)*16 + 2k(+1)

  for (int h = 0; h < H_; ++h) {
    // E2: xl / xr projections via MFMA -> f16 tiles, no activation
    gemm_e<true, false>(aF, wlp + h * 16384, bl + h * D_, 0.f, sXlg, lane, wv);
    gemm_e<true, false>(aF, wrp + h * 16384, br + h * D_, 0.f, sXrg, lane, wv);
    syncb();
    // E3: edge exp-logits (4 lanes/edge, packed f16 math + fdot2)
    {
      const int e = tg >> 2, qu = tg & 3;
      const int sn = sSrc[grp][e], dn = sDst[grp][e];
      const int ewb = (sWt[grp][e] << 9) + (h << 7);
      float dx = 0.f, dy = 0.f;
#pragma unroll
      for (int ch = 0; ch < 4; ++ch) {
        const int dd = qu * 32 + ch * 8;
        const uint4e xlu = *(const uint4e*)&sXlg[boff(sn, dd)];
        const uint4e xru = *(const uint4e*)&sXrg[boff(dn, dd)];
        const uint4e ewu = *(const uint4e*)&sEW[ewb + dd];
        const uint4e atu = *(const uint4e*)&sAtt[(h << 7) + dd];
#pragma unroll
        for (int k = 0; k < 4; ++k) {
          half2e z = u2h(xlu[k]) + u2h(xru[k]) + u2h(ewu[k]);
          z = __builtin_elementwise_max(z, z * pslope);
          if (k & 1) dy = __builtin_amdgcn_fdot2(z, u2h(atu[k]), dy, false);
          else       dx = __builtin_amdgcn_fdot2(z, u2h(atu[k]), dx, false);
        }
      }
      float dot = dx + dy;
      dot += __shfl_xor(dot, 1);
      dot += __shfl_xor(dot, 2);
      const float ex = (sEm[grp][e] > 0.f) ? __expf(dot) : 0.f;
      if (qu == 0) sExpE[e] = ex;
    }
    // E4: self-loop exp-logit (8 lanes/node, packed f16)
    {
      const int n = tg >> 3, l8 = tg & 7;
      const half2e c02 = {(_Float16)sC0[grp][n], (_Float16)sC0[grp][n]};
      const half2e c12 = {(_Float16)sC1[grp][n], (_Float16)sC1[grp][n]};
      float dx = 0.f, dy = 0.f;
#pragma unroll
      for (int ch = 0; ch < 2; ++ch) {
        const int dd = (l8 << 4) + ch * 8;
        const uint4e xlu = *(const uint4e*)&sXlg[boff(n, dd)];
        const uint4e xru = *(const uint4e*)&sXrg[boff(n, dd)];
        const uint4e e0u = *(const uint4e*)&sEW[(h << 7) + dd];
        const uint4e e1u = *(const uint4e*)&sEW[512 + (h << 7) + dd];
        const uint4e atu = *(const uint4e*)&sAtt[(h << 7) + dd];
#pragma unroll
        for (int k = 0; k < 4; ++k) {
          half2e lw = u2h(e0u[k]) * c02 + u2h(e1u[k]) * c12;
          half2e z = u2h(xlu[k]) + u2h(xru[k]) + lw;
          z = __builtin_elementwise_max(z, z * pslope);
          if (k & 1) dy = __builtin_amdgcn_fdot2(z, u2h(atu[k]), dy, false);
          else       dx = __builtin_amdgcn_fdot2(z, u2h(atu[k]), dx, false);
        }
      }
      float dot = dx + dy;
      dot += __shfl_xor(dot, 1);
      dot += __shfl_xor(dot, 2);
      dot += __shfl_xor(dot, 4);
      if (l8 == 0) sExpS[n] = __expf(dot);
    }
    syncb();
    // E6: den pass then packed-f16 aggregation directly into accA/accB
    {
      const int n = tg >> 3, l8 = tg & 7, db = l8 << 4;
      const float es = sExpS[n];
      const u64 mb = sInc[grp][n];
      float den = es;
      u64 m2 = mb;
      while (m2) { const int e = __builtin_ctzll(m2); m2 &= m2 - 1; den += sExpE[e]; }
      const float rd = 0.25f / den;
      m2 = mb;
      while (m2) {
        const int e = __builtin_ctzll(m2); m2 &= m2 - 1;
        const _Float16 wh = (_Float16)(rd * sExpE[e]);
        const half2e w2 = {wh, wh};
        const int sn = sSrc[grp][e];
        const uint4e a0 = *(const uint4e*)&sXlg[boff(sn, db)];
        const uint4e a1 = *(const uint4e*)&sXlg[boff(sn, db + 8)];
#pragma unroll
        for (int k = 0; k < 4; ++k) {
          accA[k] = u2h(a0[k]) * w2 + accA[k];
          accB[k] = u2h(a1[k]) * w2 + accB[k];
        }
      }
      const _Float16 wsh = (_Float16)(rd * es);
      const half2e ws2 = {wsh, wsh};
      const uint4e s0 = *(const uint4e*)&sXlg[boff(n, db)];
      const uint4e s1 = *(const uint4e*)&sXlg[boff(n, db + 8)];
#pragma unroll
      for (int k = 0; k < 4; ++k) {
        accA[k] = u2h(s0[k]) * ws2 + accA[k];
        accB[k] = u2h(s1[k]) * ws2 + accB[k];
      }
    }
    syncb();
  }

  // ---- gout = head-mean + gat_b -> bf16 A-matrix in sX (tables now dead) ----
  {
    const int n = tg >> 3, l8 = tg & 7, db = l8 << 4;
    const float4 g0 = *(const float4*)&gatb[db];
    const float4 g1 = *(const float4*)&gatb[db + 4];
    const float4 g2 = *(const float4*)&gatb[db + 8];
    const float4 g3 = *(const float4*)&gatb[db + 12];
    const float gv[16] = {g0.x, g0.y, g0.z, g0.w, g1.x, g1.y, g1.z, g1.w,
                          g2.x, g2.y, g2.z, g2.w, g3.x, g3.y, g3.z, g3.w};
    uint4e o0, o1;
    unsigned* po0 = (unsigned*)&o0;
    unsigned* po1 = (unsigned*)&o1;
#pragma unroll
    for (int k = 0; k < 4; ++k) {
      po0[k] = cvtpk((float)accA[k].x + gv[2 * k], (float)accA[k].y + gv[2 * k + 1]);
      po1[k] = cvtpk((float)accB[k].x + gv[8 + 2 * k], (float)accB[k].y + gv[8 + 2 * k + 1]);
    }
    *(uint4e*)&sXg[boff(n, db)] = o0;
    *(uint4e*)&sXg[boff(n, db + 8)] = o1;
  }
  syncb();

  // ---- FFN via MFMA (bf16 tiles) ----
  {
    short8 aG[2][4];
#pragma unroll
    for (int c = 0; c < 2; ++c)
#pragma unroll
      for (int q = 0; q < 4; ++q)
        aG[c][q] = *(const short8*)&sXg[boff(c * 16 + (lane & 15), q * 32 + ((lane >> 4) << 3))];
    gemm_e<false, true>(aG, w1p, b1, 0.01f, sXlg, lane, wv);
    syncb();
#pragma unroll
    for (int c = 0; c < 2; ++c)
#pragma unroll
      for (int q = 0; q < 4; ++q)
        aG[c][q] = *(const short8*)&sXlg[boff(c * 16 + (lane & 15), q * 32 + ((lane >> 4) << 3))];
    gemm_e<false, false>(aG, w2p, b2, 0.f, sXrg, lane, wv);
  }
  syncb();

  // ---- masked mean pool (sX region dead again -> sPool lives there) ----
  if (tg < D_) {
    float acc = 0.f;
    for (int n = 0; n < N_; ++n) acc = fmaf(b2f(sXrg[boff(n, tg)]), sNm[grp][n], acc);
    sPool[tg] = acc * (1.f / fmaxf(sNmSum[grp], 1.f)) * sValid[grp];
  }
  syncb();
  // ---- LN2 + store ----
  if (tg < 64) {
    const float v0 = sPool[tg], v1 = sPool[tg + 64];
    float s = v0 + v1, ss = v0 * v0 + v1 * v1;
#pragma unroll
    for (int m = 1; m < 64; m <<= 1) { s += __shfl_xor(s, m); ss += __shfl_xor(ss, m); }
    const float mu = s * (1.f / 128.f);
    const float inv = rsqrtf(ss * (1.f / 128.f) - mu * mu + 1e-5f);
    float* op = out + (size_t)g * D_;
    __builtin_nontemporal_store((v0 - mu) * inv * ln2g[tg] + ln2b[tg], op + tg);
    __builtin_nontemporal_store((v1 - mu) * inv * ln2g[tg + 64] + ln2b[tg + 64], op + tg + 64);
  }
}

extern "C" void kernel_launch(void* const* d_in, const int* in_sizes, int n_in,
                              void* d_out, int out_size, void* d_ws, size_t ws_size,
                              hipStream_t stream) {
  (void)in_sizes; (void)n_in; (void)out_size; (void)ws_size;
  const float* qe   = (const float*)d_in[0];
  const int*   qm   = (const int*)d_in[1];
  const int*   ei   = (const int*)d_in[2];
  const int*   ew   = (const int*)d_in[3];
  const int*   em   = (const int*)d_in[4];
  const float* ln1g = (const float*)d_in[5];
  const float* ln1b = (const float*)d_in[6];
  const float* embT = (const float*)d_in[7];
  const float* Wl   = (const float*)d_in[8];
  const float* bl   = (const float*)d_in[9];
  const float* Wr   = (const float*)d_in[10];
  const float* br   = (const float*)d_in[11];
  const float* We   = (const float*)d_in[12];
  const float* att  = (const float*)d_in[13];
  const float* gatb = (const float*)d_in[14];
  const float* W1   = (const float*)d_in[15];
  const float* b1   = (const float*)d_in[16];
  const float* W2   = (const float*)d_in[17];
  const float* b2   = (const float*)d_in[18];
  const float* ln2g = (const float*)d_in[19];
  const float* ln2b = (const float*)d_in[20];
  float* out = (float*)d_out;
  unsigned char* ws = (unsigned char*)d_ws;

  pack_weights<<<dim3(324), dim3(256), 0, stream>>>(Wl, Wr, W1, W2, embT, We, ws);
  gat_main<<<dim3(G_ / 2), dim3(512), 0, stream>>>(ws, qe, ln1g, ln1b, qm, ei, ew, em,
                                                   bl, br, att, gatb, b1, b2, ln2g, ln2b, out);
}

// Round 18
// 137.325 us; speedup vs baseline: 1.1086x; 1.1086x over previous
//
#include <hip/hip_runtime.h>
#include <math.h>

#define B_ 64
#define Q_ 50
#define N_ 32
#define E_ 64
#define D_ 128
#define H_ 4
#define EDIM_ 8
#define G_ (B_*Q_)

// d_ws layout (bytes)
#define WLP_OFF 0          // 4h x 4q x 128n x 32kk bf16 = 131072 B
#define WRP_OFF 131072
#define W1P_OFF 262144     // 4q x 128n x 32kk bf16 = 32768 B
#define W2P_OFF 294912
#define EW_OFF  327680     // 2 x 512 f32 = 4096 B  (emb_table @ We)

typedef __attribute__((ext_vector_type(8))) short short8;
typedef __attribute__((ext_vector_type(4))) float f32x4;
typedef __attribute__((ext_vector_type(4))) unsigned uint4e;
typedef __attribute__((ext_vector_type(2))) unsigned uint2e;
typedef __attribute__((ext_vector_type(2))) _Float16 half2e;
typedef __attribute__((ext_vector_type(2))) __fp16 fp16v2;
typedef unsigned short ushort_t;
typedef unsigned long long u64;

// f16/bf16 [32][128] LDS tile, XOR-swizzled at 16B granularity over 16 rows.
__device__ __forceinline__ int boff(int r, int d) {
  return (r << 7) + ((d & 0x78) ^ ((r & 15) << 3)) + (d & 7);
}

__device__ __forceinline__ ushort_t f2b(float f) {
  unsigned u = __float_as_uint(f);
  u += 0x7fffu + ((u >> 16) & 1u);
  return (ushort_t)(u >> 16);
}
__device__ __forceinline__ float b2f(ushort_t u) {
  return __uint_as_float(((unsigned)u) << 16);
}
// packed f32->bf16 (RNE), 2 elems / inst
__device__ __forceinline__ unsigned cvtpk(float lo, float hi) {
  unsigned r;
  asm("v_cvt_pk_bf16_f32 %0, %1, %2" : "=v"(r) : "v"(lo), "v"(hi));
  return r;
}
// packed f32->f16 (RTZ), 2 elems / inst, returns raw u32
__device__ __forceinline__ unsigned pkrtz(float lo, float hi) {
  union { fp16v2 h; unsigned u; } x;
  x.h = __builtin_amdgcn_cvt_pkrtz(lo, hi);
  return x.u;
}
__device__ __forceinline__ half2e u2h(unsigned u) {
  union { unsigned u; half2e h; } x; x.u = u; return x.h;
}
__device__ __forceinline__ float leakyf(float v, float s) {
  return fmaxf(v, s * v);   // valid for 0<s<1
}
// barrier that drains LDS only (keeps global loads in flight)
__device__ __forceinline__ void syncb() {
  asm volatile("s_waitcnt lgkmcnt(0)" ::: "memory");
  __builtin_amdgcn_s_barrier();
  asm volatile("" ::: "memory");
}

// ---------------- prep kernel: pack weights bf16 + EW = emb_table @ We ----------------
__global__ __launch_bounds__(256)
void pack_weights(const float* __restrict__ Wl, const float* __restrict__ Wr,
                  const float* __restrict__ W1, const float* __restrict__ W2,
                  const float* __restrict__ embT, const float* __restrict__ We,
                  unsigned char* __restrict__ ws)
{
  const int i = blockIdx.x * 256 + threadIdx.x;
  ushort_t* wlp = (ushort_t*)(ws + WLP_OFF);
  ushort_t* wrp = (ushort_t*)(ws + WRP_OFF);
  ushort_t* w1p = (ushort_t*)(ws + W1P_OFF);
  ushort_t* w2p = (ushort_t*)(ws + W2P_OFF);
  float* ew = (float*)(ws + EW_OFF);
  if (i < 65536) {
    // packed: idx = ((h*4+q)*128 + n)*32 + kk  <=  W[(q*32+kk)][h*128+n]
    const int kk = i & 31, n = (i >> 5) & 127, q = (i >> 12) & 3, h = i >> 14;
    wlp[i] = f2b(Wl[(q * 32 + kk) * (H_ * D_) + h * D_ + n]);
    wrp[i] = f2b(Wr[(q * 32 + kk) * (H_ * D_) + h * D_ + n]);
  } else if (i < 65536 + 16384) {
    const int j = i - 65536;
    const int kk = j & 31, n = (j >> 5) & 127, q = j >> 12;
    w1p[j] = f2b(W1[(q * 32 + kk) * D_ + n]);
    w2p[j] = f2b(W2[(q * 32 + kk) * D_ + n]);
  } else if (i < 65536 + 16384 + 1024) {
    const int j = i - 65536 - 16384;
    const int w = j >> 9, hd = j & 511;   // ew layout: [w][h*128+d]
    float a = 0.f;
#pragma unroll
    for (int k = 0; k < EDIM_; ++k) a = fmaf(embT[w * EDIM_ + k], We[k * (H_ * D_) + hd], a);
    ew[j] = a;
  }
}

// MFMA GEMM (swapped operands): [32 x 128] = A[32x128] @ W[128x128].
// F16OUT: write packed f16 (consumed by packed-math phases); else bf16 (next MFMA A-frag).
// LEAKY: apply leaky(slope) activation.
template <bool F16OUT, bool LEAKY>
__device__ __forceinline__ void gemm_e(const short8 aF[2][4], const ushort_t* __restrict__ Bp,
                                       const float* __restrict__ bias, float slope,
                                       ushort_t* __restrict__ dst, int lane, int nq)
{
#pragma unroll
  for (int nt = 0; nt < 2; ++nt) {
    const int colw = nq * 32 + nt * 16 + (lane & 15);
    const int oc0 = nq * 32 + nt * 16 + ((lane >> 4) << 2);
    const float4 bb = *(const float4*)&bias[oc0];
    f32x4 acc0 = {0.f, 0.f, 0.f, 0.f}, acc1 = {0.f, 0.f, 0.f, 0.f};
#pragma unroll
    for (int q = 0; q < 4; ++q) {
      const short8 b = *(const short8*)&Bp[((q << 7) + colw) * 32 + ((lane >> 4) << 3)];
      acc0 = __builtin_amdgcn_mfma_f32_16x16x32_bf16(b, aF[0][q], acc0, 0, 0, 0);
      acc1 = __builtin_amdgcn_mfma_f32_16x16x32_bf16(b, aF[1][q], acc1, 0, 0, 0);
    }
#pragma unroll
    for (int cc = 0; cc < 2; ++cc) {
      const f32x4 a = cc ? acc1 : acc0;
      const int node = cc * 16 + (lane & 15);
      float v0 = a[0] + bb.x, v1 = a[1] + bb.y, v2 = a[2] + bb.z, v3 = a[3] + bb.w;
      if (LEAKY) {
        v0 = leakyf(v0, slope); v1 = leakyf(v1, slope);
        v2 = leakyf(v2, slope); v3 = leakyf(v3, slope);
      }
      uint2e o;
      if (F16OUT) {
        o.x = pkrtz(v0, v1);
        o.y = pkrtz(v2, v3);
      } else {
        o.x = cvtpk(v0, v1);
        o.y = cvtpk(v2, v3);
      }
      *(uint2e*)&dst[boff(node, oc0)] = o;
    }
  }
}

// ---------------- main fused kernel: one block per group, ALL heads per phase ----------------
__global__ __launch_bounds__(256, 4)
void gat_main(const unsigned char* __restrict__ ws,
              const float* __restrict__ qe,
              const float* __restrict__ ln1g, const float* __restrict__ ln1b,
              const int* __restrict__ qmask, const int* __restrict__ eidx,
              const int* __restrict__ ewt, const int* __restrict__ emsk,
              const float* __restrict__ bl, const float* __restrict__ br,
              const float* __restrict__ att, const float* __restrict__ gatb,
              const float* __restrict__ b1, const float* __restrict__ b2,
              const float* __restrict__ ln2g, const float* __restrict__ ln2b,
              float* __restrict__ out)
{
  const int g = blockIdx.x, t = threadIdx.x;
  const int lane = t & 63, wave = t >> 6;

  // 8 tiles: T(h)=xl_h (h=0..3), T(4+h)=xr_h. T(0) doubles as LN1 A-matrix (prologue),
  // gout (FFN A), T(4)=FFN h1, T(1)=FFN h2.
  __shared__ __align__(16) ushort_t sT[8 * N_ * D_];
  __shared__ __align__(16) ushort_t sEW[1024];   // [w][h][d] f16
  __shared__ __align__(16) ushort_t sAtt[512];   // [h][d] f16
  __shared__ float sExpE[H_][E_];
  __shared__ float sExpS[H_][N_];
  __shared__ float sPool[D_];
  __shared__ u64 sInc[N_];
  __shared__ int sSrc[E_], sDst[E_], sWt[E_];
  __shared__ float sEm[E_], sNm[N_], sC0[N_], sC1[N_];
  __shared__ float sValid, sNmSum;
#define T(i) (sT + (i) * (N_ * D_))

  const ushort_t* wlp = (const ushort_t*)(ws + WLP_OFF);
  const ushort_t* wrp = (const ushort_t*)(ws + WRP_OFF);
  const ushort_t* w1p = (const ushort_t*)(ws + W1P_OFF);
  const ushort_t* w2p = (const ushort_t*)(ws + W2P_OFF);

  // ---- Phase A: LN1 -> bf16 T(0); tables; edge data ----
  {
    const int r = t >> 3, d0 = (t & 7) << 4;
    const f32x4* src4 = (const f32x4*)(qe + ((size_t)g * N_ + r) * D_ + d0);
    f32x4 v4[4];
#pragma unroll
    for (int p = 0; p < 4; ++p) v4[p] = __builtin_nontemporal_load(src4 + p);
    const float* v = (const float*)v4;
    float s = 0.f, ss = 0.f;
#pragma unroll
    for (int i = 0; i < 16; ++i) { float x = v[i]; s += x; ss += x * x; }
#pragma unroll
    for (int m = 1; m < 8; m <<= 1) { s += __shfl_xor(s, m); ss += __shfl_xor(ss, m); }
    const float mu = s * (1.f / 128.f);
    const float inv = rsqrtf(ss * (1.f / 128.f) - mu * mu + 1e-5f);
    const f32x4* gg = (const f32x4*)&ln1g[d0];
    const f32x4* bb = (const f32x4*)&ln1b[d0];
    float o[16];
#pragma unroll
    for (int p = 0; p < 4; ++p) {
      const f32x4 g4 = gg[p], b4 = bb[p];
#pragma unroll
      for (int k = 0; k < 4; ++k)
        o[p * 4 + k] = (v[p * 4 + k] - mu) * inv * g4[k] + b4[k];
    }
    uint4e w0, w1;
    w0.x = cvtpk(o[0], o[1]);  w0.y = cvtpk(o[2], o[3]);
    w0.z = cvtpk(o[4], o[5]);  w0.w = cvtpk(o[6], o[7]);
    w1.x = cvtpk(o[8], o[9]);  w1.y = cvtpk(o[10], o[11]);
    w1.z = cvtpk(o[12], o[13]); w1.w = cvtpk(o[14], o[15]);
    *(uint4e*)&T(0)[boff(r, d0)] = w0;
    *(uint4e*)&T(0)[boff(r, d0 + 8)] = w1;
  }
  {
    const float* ewg = (const float*)(ws + EW_OFF);
    const f32x4 e4 = *(const f32x4*)&ewg[t << 2];
    uint2e p;
    p.x = pkrtz(e4[0], e4[1]);
    p.y = pkrtz(e4[2], e4[3]);
    *(uint2e*)&sEW[t << 2] = p;
    if (t < 128) {
      const f32x4 a4 = *(const f32x4*)&att[t << 2];
      uint2e q;
      q.x = pkrtz(a4[0], a4[1]);
      q.y = pkrtz(a4[2], a4[3]);
      *(uint2e*)&sAtt[t << 2] = q;
    }
  }
  if (t < E_) {
    sSrc[t] = eidx[(size_t)g * 2 * E_ + t];
    sDst[t] = eidx[(size_t)g * 2 * E_ + E_ + t];
    sWt[t] = ewt[(size_t)g * E_ + t];
    sEm[t] = (float)emsk[(size_t)g * E_ + t];
  } else if (t < 96) {
    sNm[t - 64] = (float)qmask[(size_t)g * N_ + (t - 64)];
  }
  syncb();

  // ---- A fragments + ballot masks ----
  short8 aF[2][4];
#pragma unroll
  for (int c = 0; c < 2; ++c)
#pragma unroll
    for (int q = 0; q < 4; ++q)
      aF[c][q] = *(const short8*)&T(0)[boff(c * 16 + (lane & 15), q * 32 + ((lane >> 4) << 3))];
  {
    const int dl = sDst[lane];
    const float eml = sEm[lane];
    const int wtl = sWt[lane];
    const bool val = eml > 0.f;
    const u64 wt0m = __ballot(wtl == 0);
#pragma unroll
    for (int k = 0; k < 8; ++k) {
      const int n = wave * 8 + k;
      const u64 inc = __ballot(val && dl == n);
      if (lane == k) {
        sInc[n] = inc;
        const float cnt = (float)__popcll(inc);
        const float c0 = (float)__popcll(inc & wt0m);
        const float rinv = 1.f / fmaxf(cnt, 1.f);
        sC0[n] = c0 * rinv;
        sC1[n] = (cnt - c0) * rinv;
      }
    }
    if (wave == 3) {
      float nmv = (lane < 32) ? sNm[lane] : 0.f;
      float emv = eml;
#pragma unroll
      for (int m = 1; m < 64; m <<= 1) { nmv += __shfl_xor(nmv, m); emv += __shfl_xor(emv, m); }
      if (lane == 0) {
        sNmSum = nmv;
        sValid = (nmv > 0.f && emv > 0.f) ? 1.f : 0.f;
      }
    }
  }
  syncb();   // aF extracted -> T(0) free

  // ---- E2: ALL 8 projections in one phase (8 GEMMs of independent MFMA+loads) ----
#pragma unroll
  for (int h = 0; h < H_; ++h) {
    gemm_e<true, false>(aF, wlp + h * 16384, bl + h * D_, 0.f, T(h), lane, wave);
    gemm_e<true, false>(aF, wrp + h * 16384, br + h * D_, 0.f, T(4 + h), lane, wave);
  }
  syncb();

  const half2e pslope = {(_Float16)0.2f, (_Float16)0.2f};

  // ---- E3: edge exp-logits, ALL heads (4 lanes/edge, 4 indep dot chains) ----
  {
    const int e = t >> 2, qu = t & 3;
    const int sn = sSrc[e], dn = sDst[e];
    const int wb = sWt[e] << 9;
    float dx[H_] = {}, dy[H_] = {};
#pragma unroll
    for (int ch = 0; ch < 4; ++ch) {
      const int dd = qu * 32 + ch * 8;
      const int osn = boff(sn, dd), odn = boff(dn, dd);
#pragma unroll
      for (int h = 0; h < H_; ++h) {
        const uint4e xlu = *(const uint4e*)&T(h)[osn];
        const uint4e xru = *(const uint4e*)&T(4 + h)[odn];
        const uint4e ewu = *(const uint4e*)&sEW[wb + (h << 7) + dd];
        const uint4e atu = *(const uint4e*)&sAtt[(h << 7) + dd];
#pragma unroll
        for (int k = 0; k < 4; ++k) {
          half2e z = u2h(xlu[k]) + u2h(xru[k]) + u2h(ewu[k]);
          z = __builtin_elementwise_max(z, z * pslope);
          if (k & 1) dy[h] = __builtin_amdgcn_fdot2(z, u2h(atu[k]), dy[h], false);
          else       dx[h] = __builtin_amdgcn_fdot2(z, u2h(atu[k]), dx[h], false);
        }
      }
    }
    const bool ve = sEm[e] > 0.f;
#pragma unroll
    for (int h = 0; h < H_; ++h) {
      float dot = dx[h] + dy[h];
      dot += __shfl_xor(dot, 1);
      dot += __shfl_xor(dot, 2);
      if (qu == 0) sExpE[h][e] = ve ? __expf(dot) : 0.f;
    }
  }
  // ---- E4: self-loop exp-logits, ALL heads (8 lanes/node) ----
  {
    const int n = t >> 3, l8 = t & 7;
    const half2e c02 = {(_Float16)sC0[n], (_Float16)sC0[n]};
    const half2e c12 = {(_Float16)sC1[n], (_Float16)sC1[n]};
    float dx[H_] = {}, dy[H_] = {};
#pragma unroll
    for (int ch = 0; ch < 2; ++ch) {
      const int dd = (l8 << 4) + ch * 8;
      const int on = boff(n, dd);
#pragma unroll
      for (int h = 0; h < H_; ++h) {
        const uint4e xlu = *(const uint4e*)&T(h)[on];
        const uint4e xru = *(const uint4e*)&T(4 + h)[on];
        const uint4e e0u = *(const uint4e*)&sEW[(h << 7) + dd];
        const uint4e e1u = *(const uint4e*)&sEW[512 + (h << 7) + dd];
        const uint4e atu = *(const uint4e*)&sAtt[(h << 7) + dd];
#pragma unroll
        for (int k = 0; k < 4; ++k) {
          half2e lw = u2h(e0u[k]) * c02 + u2h(e1u[k]) * c12;
          half2e z = u2h(xlu[k]) + u2h(xru[k]) + lw;
          z = __builtin_elementwise_max(z, z * pslope);
          if (k & 1) dy[h] = __builtin_amdgcn_fdot2(z, u2h(atu[k]), dy[h], false);
          else       dx[h] = __builtin_amdgcn_fdot2(z, u2h(atu[k]), dx[h], false);
        }
      }
    }
#pragma unroll
    for (int h = 0; h < H_; ++h) {
      float dot = dx[h] + dy[h];
      dot += __shfl_xor(dot, 1);
      dot += __shfl_xor(dot, 2);
      dot += __shfl_xor(dot, 4);
      if (l8 == 0) sExpS[h][n] = __expf(dot);
    }
  }
  syncb();

  // ---- E6: den + aggregation, ALL heads -> head-mean acc ----
  half2e accA[4] = {}, accB[4] = {};
  {
    const int n = t >> 3, l8 = t & 7, db = l8 << 4;
    const u64 mb = sInc[n];
    float den[H_];
#pragma unroll
    for (int h = 0; h < H_; ++h) den[h] = sExpS[h][n];
    u64 m2 = mb;
    while (m2) {
      const int e = __builtin_ctzll(m2); m2 &= m2 - 1;
#pragma unroll
      for (int h = 0; h < H_; ++h) den[h] += sExpE[h][e];
    }
    float rd[H_];
#pragma unroll
    for (int h = 0; h < H_; ++h) rd[h] = 0.25f / den[h];
    m2 = mb;
    while (m2) {
      const int e = __builtin_ctzll(m2); m2 &= m2 - 1;
      const int sn = sSrc[e];
      const int o0 = boff(sn, db), o1 = boff(sn, db + 8);
#pragma unroll
      for (int h = 0; h < H_; ++h) {
        const _Float16 wh = (_Float16)(rd[h] * sExpE[h][e]);
        const half2e w2 = {wh, wh};
        const uint4e a0 = *(const uint4e*)&T(h)[o0];
        const uint4e a1 = *(const uint4e*)&T(h)[o1];
#pragma unroll
        for (int k = 0; k < 4; ++k) {
          accA[k] = u2h(a0[k]) * w2 + accA[k];
          accB[k] = u2h(a1[k]) * w2 + accB[k];
        }
      }
    }
    const int o0 = boff(n, db), o1 = boff(n, db + 8);
#pragma unroll
    for (int h = 0; h < H_; ++h) {
      const _Float16 wsh = (_Float16)(rd[h] * sExpS[h][n]);
      const half2e ws2 = {wsh, wsh};
      const uint4e s0 = *(const uint4e*)&T(h)[o0];
      const uint4e s1 = *(const uint4e*)&T(h)[o1];
#pragma unroll
      for (int k = 0; k < 4; ++k) {
        accA[k] = u2h(s0[k]) * ws2 + accA[k];
        accB[k] = u2h(s1[k]) * ws2 + accB[k];
      }
    }
  }
  syncb();

  // ---- gout = head-mean + gat_b -> bf16 A-matrix in T(0) ----
  {
    const int n = t >> 3, l8 = t & 7, db = l8 << 4;
    const float4 g0 = *(const float4*)&gatb[db];
    const float4 g1 = *(const float4*)&gatb[db + 4];
    const float4 g2 = *(const float4*)&gatb[db + 8];
    const float4 g3 = *(const float4*)&gatb[db + 12];
    const float gv[16] = {g0.x, g0.y, g0.z, g0.w, g1.x, g1.y, g1.z, g1.w,
                          g2.x, g2.y, g2.z, g2.w, g3.x, g3.y, g3.z, g3.w};
    uint4e o0, o1;
    unsigned* po0 = (unsigned*)&o0;
    unsigned* po1 = (unsigned*)&o1;
#pragma unroll
    for (int k = 0; k < 4; ++k) {
      po0[k] = cvtpk((float)accA[k].x + gv[2 * k], (float)accA[k].y + gv[2 * k + 1]);
      po1[k] = cvtpk((float)accB[k].x + gv[8 + 2 * k], (float)accB[k].y + gv[8 + 2 * k + 1]);
    }
    *(uint4e*)&T(0)[boff(n, db)] = o0;
    *(uint4e*)&T(0)[boff(n, db + 8)] = o1;
  }
  syncb();

  // ---- FFN via MFMA: T(0) -> T(4) -> T(1) ----
  {
    short8 aG[2][4];
#pragma unroll
    for (int c = 0; c < 2; ++c)
#pragma unroll
      for (int q = 0; q < 4; ++q)
        aG[c][q] = *(const short8*)&T(0)[boff(c * 16 + (lane & 15), q * 32 + ((lane >> 4) << 3))];
    gemm_e<false, true>(aG, w1p, b1, 0.01f, T(4), lane, wave);
    syncb();
#pragma unroll
    for (int c = 0; c < 2; ++c)
#pragma unroll
      for (int q = 0; q < 4; ++q)
        aG[c][q] = *(const short8*)&T(4)[boff(c * 16 + (lane & 15), q * 32 + ((lane >> 4) << 3))];
    gemm_e<false, false>(aG, w2p, b2, 0.f, T(1), lane, wave);
  }
  syncb();

  // ---- masked mean pool ----
  if (t < D_) {
    float acc = 0.f;
    for (int n = 0; n < N_; ++n) acc = fmaf(b2f(T(1)[boff(n, t)]), sNm[n], acc);
    sPool[t] = acc * (1.f / fmaxf(sNmSum, 1.f)) * sValid;
  }
  syncb();
  // ---- LN2 + store ----
  if (t < 64) {
    const float v0 = sPool[t], v1 = sPool[t + 64];
    float s = v0 + v1, ss = v0 * v0 + v1 * v1;
#pragma unroll
    for (int m = 1; m < 64; m <<= 1) { s += __shfl_xor(s, m); ss += __shfl_xor(ss, m); }
    const float mu = s * (1.f / 128.f);
    const float inv = rsqrtf(ss * (1.f / 128.f) - mu * mu + 1e-5f);
    float* op = out + (size_t)g * D_;
    __builtin_nontemporal_store((v0 - mu) * inv * ln2g[t] + ln2b[t], op + t);
    __builtin_nontemporal_store((v1 - mu) * inv * ln2g[t + 64] + ln2b[t + 64], op + t + 64);
  }
#undef T
}

extern "C" void kernel_launch(void* const* d_in, const int* in_sizes, int n_in,
                              void* d_out, int out_size, void* d_ws, size_t ws_size,
                              hipStream_t stream) {
  (void)in_sizes; (void)n_in; (void)out_size; (void)ws_size;
  const float* qe   = (const float*)d_in[0];
  const int*   qm   = (const int*)d_in[1];
  const int*   ei   = (const int*)d_in[2];
  const int*   ew   = (const int*)d_in[3];
  const int*   em   = (const int*)d_in[4];
  const float* ln1g = (const float*)d_in[5];
  const float* ln1b = (const float*)d_in[6];
  const float* embT = (const float*)d_in[7];
  const float* Wl   = (const float*)d_in[8];
  const float* bl   = (const float*)d_in[9];
  const float* Wr   = (const float*)d_in[10];
  const float* br   = (const float*)d_in[11];
  const float* We   = (const float*)d_in[12];
  const float* att  = (const float*)d_in[13];
  const float* gatb = (const float*)d_in[14];
  const float* W1   = (const float*)d_in[15];
  const float* b1   = (const float*)d_in[16];
  const float* W2   = (const float*)d_in[17];
  const float* b2   = (const float*)d_in[18];
  const float* ln2g = (const float*)d_in[19];
  const float* ln2b = (const float*)d_in[20];
  float* out = (float*)d_out;
  unsigned char* ws = (unsigned char*)d_ws;

  pack_weights<<<dim3(324), dim3(256), 0, stream>>>(Wl, Wr, W1, W2, embT, We, ws);
  gat_main<<<dim3(G_), dim3(256), 0, stream>>>(ws, qe, ln1g, ln1b, qm, ei, ew, em,
                                               bl, br, att, gatb, b1, b2, ln2g, ln2b, out);
}

// Round 21
// 127.026 us; speedup vs baseline: 1.1985x; 1.0811x over previous
//
#include <hip/hip_runtime.h>
#include <math.h>

#define B_ 64
#define Q_ 50
#define N_ 32
#define E_ 64
#define D_ 128
#define H_ 4
#define EDIM_ 8
#define G_ (B_*Q_)

// d_ws layout (bytes)
#define WLP_OFF 0          // 4h x 4q x 128n x 32kk bf16 = 131072 B
#define WRP_OFF 131072
#define W1P_OFF 262144     // 4q x 128n x 32kk bf16 = 32768 B
#define W2P_OFF 294912
#define EW_OFF  327680     // 2 x 512 f32 = 4096 B  (emb_table @ We)

typedef __attribute__((ext_vector_type(8))) short short8;
typedef __attribute__((ext_vector_type(4))) float f32x4;
typedef __attribute__((ext_vector_type(4))) unsigned uint4e;
typedef __attribute__((ext_vector_type(2))) unsigned uint2e;
typedef __attribute__((ext_vector_type(2))) _Float16 half2e;
typedef __attribute__((ext_vector_type(2))) __fp16 fp16v2;
typedef unsigned short ushort_t;
typedef unsigned long long u64;

// bf16/f16 [32][128] LDS tile, XOR-swizzled at 16B granularity (8 elems).
__device__ __forceinline__ int boff(int r, int d) {
  return (r << 7) + ((d & 0x78) ^ ((r & 7) << 3)) + (d & 7);
}

__device__ __forceinline__ ushort_t f2b(float f) {
  unsigned u = __float_as_uint(f);
  u += 0x7fffu + ((u >> 16) & 1u);
  return (ushort_t)(u >> 16);
}
__device__ __forceinline__ float b2f(ushort_t u) {
  return __uint_as_float(((unsigned)u) << 16);
}
// packed f32->bf16 (RNE), 2 elems / inst
__device__ __forceinline__ unsigned cvtpk(float lo, float hi) {
  unsigned r;
  asm("v_cvt_pk_bf16_f32 %0, %1, %2" : "=v"(r) : "v"(lo), "v"(hi));
  return r;
}
// packed f32->f16 (RTZ), 2 elems / inst, returns raw u32
__device__ __forceinline__ unsigned pkrtz(float lo, float hi) {
  union { fp16v2 h; unsigned u; } x;
  x.h = __builtin_amdgcn_cvt_pkrtz(lo, hi);
  return x.u;
}
__device__ __forceinline__ half2e u2h(unsigned u) {
  union { unsigned u; half2e h; } x; x.u = u; return x.h;
}
__device__ __forceinline__ float leakyf(float v, float s) {
  return fmaxf(v, s * v);   // valid for 0<s<1
}
// barrier that drains LDS only (keeps global loads in flight)
__device__ __forceinline__ void syncb() {
  asm volatile("s_waitcnt lgkmcnt(0)" ::: "memory");
  __builtin_amdgcn_s_barrier();
  asm volatile("" ::: "memory");
}

// ---------------- prep kernel: pack weights bf16 + EW = emb_table @ We ----------------
__global__ __launch_bounds__(256)
void pack_weights(const float* __restrict__ Wl, const float* __restrict__ Wr,
                  const float* __restrict__ W1, const float* __restrict__ W2,
                  const float* __restrict__ embT, const float* __restrict__ We,
                  unsigned char* __restrict__ ws)
{
  const int i = blockIdx.x * 256 + threadIdx.x;
  ushort_t* wlp = (ushort_t*)(ws + WLP_OFF);
  ushort_t* wrp = (ushort_t*)(ws + WRP_OFF);
  ushort_t* w1p = (ushort_t*)(ws + W1P_OFF);
  ushort_t* w2p = (ushort_t*)(ws + W2P_OFF);
  float* ew = (float*)(ws + EW_OFF);
  if (i < 65536) {
    // packed: idx = ((h*4+q)*128 + n)*32 + kk  <=  W[(q*32+kk)][h*128+n]
    const int kk = i & 31, n = (i >> 5) & 127, q = (i >> 12) & 3, h = i >> 14;
    wlp[i] = f2b(Wl[(q * 32 + kk) * (H_ * D_) + h * D_ + n]);
    wrp[i] = f2b(Wr[(q * 32 + kk) * (H_ * D_) + h * D_ + n]);
  } else if (i < 65536 + 16384) {
    const int j = i - 65536;
    const int kk = j & 31, n = (j >> 5) & 127, q = j >> 12;
    w1p[j] = f2b(W1[(q * 32 + kk) * D_ + n]);
    w2p[j] = f2b(W2[(q * 32 + kk) * D_ + n]);
  } else if (i < 65536 + 16384 + 1024) {
    const int j = i - 65536 - 16384;
    const int w = j >> 9, hd = j & 511;   // ew layout: [w][h*128+d]
    float a = 0.f;
#pragma unroll
    for (int k = 0; k < EDIM_; ++k) a = fmaf(embT[w * EDIM_ + k], We[k * (H_ * D_) + hd], a);
    ew[j] = a;
  }
}

// MFMA GEMM (swapped operands): [32 x 128] = A[32x128] @ W[128x128].
// F16OUT: write packed f16 (consumed by packed-math phases); else bf16 (next MFMA A-frag).
// LEAKY: apply leaky(slope) activation.
template <bool F16OUT, bool LEAKY>
__device__ __forceinline__ void gemm_e(const short8 aF[2][4], const ushort_t* __restrict__ Bp,
                                       const float* __restrict__ bias, float slope,
                                       ushort_t* __restrict__ dst, int lane, int nq)
{
#pragma unroll
  for (int nt = 0; nt < 2; ++nt) {
    const int colw = nq * 32 + nt * 16 + (lane & 15);
    const int oc0 = nq * 32 + nt * 16 + ((lane >> 4) << 2);
    const float4 bb = *(const float4*)&bias[oc0];
    f32x4 acc0 = {0.f, 0.f, 0.f, 0.f}, acc1 = {0.f, 0.f, 0.f, 0.f};
#pragma unroll
    for (int q = 0; q < 4; ++q) {
      const short8 b = *(const short8*)&Bp[((q << 7) + colw) * 32 + ((lane >> 4) << 3)];
      acc0 = __builtin_amdgcn_mfma_f32_16x16x32_bf16(b, aF[0][q], acc0, 0, 0, 0);
      acc1 = __builtin_amdgcn_mfma_f32_16x16x32_bf16(b, aF[1][q], acc1, 0, 0, 0);
    }
#pragma unroll
    for (int cc = 0; cc < 2; ++cc) {
      const f32x4 a = cc ? acc1 : acc0;
      const int node = cc * 16 + (lane & 15);
      float v0 = a[0] + bb.x, v1 = a[1] + bb.y, v2 = a[2] + bb.z, v3 = a[3] + bb.w;
      if (LEAKY) {
        v0 = leakyf(v0, slope); v1 = leakyf(v1, slope);
        v2 = leakyf(v2, slope); v3 = leakyf(v3, slope);
      }
      uint2e o;
      if (F16OUT) {
        o.x = pkrtz(v0, v1);
        o.y = pkrtz(v2, v3);
      } else {
        o.x = cvtpk(v0, v1);
        o.y = cvtpk(v2, v3);
      }
      *(uint2e*)&dst[boff(node, oc0)] = o;
    }
  }
}

// ---------------- main fused kernel: one block per group ----------------
__global__ __launch_bounds__(256, 4)
void gat_main(const unsigned char* __restrict__ ws,
              const float* __restrict__ qe,
              const float* __restrict__ ln1g, const float* __restrict__ ln1b,
              const int* __restrict__ qmask, const int* __restrict__ eidx,
              const int* __restrict__ ewt, const int* __restrict__ emsk,
              const float* __restrict__ bl, const float* __restrict__ br,
              const float* __restrict__ att, const float* __restrict__ gatb,
              const float* __restrict__ b1, const float* __restrict__ b2,
              const float* __restrict__ ln2g, const float* __restrict__ ln2b,
              float* __restrict__ out)
{
  const int g = blockIdx.x, t = threadIdx.x;
  const int lane = t & 63, wave = t >> 6;

  // sX: LN1 A-matrix during prologue; tables+softmax scratch during heads; gout for FFN; pool at end
  __shared__ __align__(16) ushort_t sX[N_ * D_];
  __shared__ __align__(16) ushort_t sXl[N_ * D_];   // xl f16 (per head); later FFN h1 bf16
  __shared__ __align__(16) ushort_t sXr[N_ * D_];   // xr f16 (per head); later FFN h2 bf16
  __shared__ u64 sInc[N_];            // per-node valid incoming-edge bitmask
  __shared__ int sSrc[E_], sDst[E_], sWt[E_];
  __shared__ float sEm[E_], sNm[N_], sC0[N_], sC1[N_];
  __shared__ float sValid, sNmSum;

  // aliases into sX region (live only between table-stage and gout)
  ushort_t* sEW  = sX;                       // [2][4][128] f16, elems 0..1023
  ushort_t* sAtt = sX + 1024;                // [4][128] f16, elems 1024..1535
  float* sExpE = (float*)(sX + 1536);        // 64 f32
  float* sExpS = (float*)(sX + 1664);        // 32 f32
  float* sPool = (float*)(sX + 1728);        // 128 f32 (post-FFN only)

  const ushort_t* wlp = (const ushort_t*)(ws + WLP_OFF);
  const ushort_t* wrp = (const ushort_t*)(ws + WRP_OFF);
  const ushort_t* w1p = (const ushort_t*)(ws + W1P_OFF);
  const ushort_t* w2p = (const ushort_t*)(ws + W2P_OFF);

  // ---- Phase A: LN1 -> bf16 swizzled LDS (nontemporal qe); stage edge data ----
  {
    const int r = t >> 3, d0 = (t & 7) << 4;
    const f32x4* src4 = (const f32x4*)(qe + ((size_t)g * N_ + r) * D_ + d0);
    f32x4 v4[4];
#pragma unroll
    for (int p = 0; p < 4; ++p) v4[p] = __builtin_nontemporal_load(src4 + p);
    const float* v = (const float*)v4;
    float s = 0.f, ss = 0.f;
#pragma unroll
    for (int i = 0; i < 16; ++i) { float x = v[i]; s += x; ss += x * x; }
#pragma unroll
    for (int m = 1; m < 8; m <<= 1) { s += __shfl_xor(s, m); ss += __shfl_xor(ss, m); }
    const float mu = s * (1.f / 128.f);
    const float inv = rsqrtf(ss * (1.f / 128.f) - mu * mu + 1e-5f);
    const f32x4* gg = (const f32x4*)&ln1g[d0];
    const f32x4* bb = (const f32x4*)&ln1b[d0];
    float o[16];
#pragma unroll
    for (int p = 0; p < 4; ++p) {
      const f32x4 g4 = gg[p], b4 = bb[p];
#pragma unroll
      for (int k = 0; k < 4; ++k)
        o[p * 4 + k] = (v[p * 4 + k] - mu) * inv * g4[k] + b4[k];
    }
    uint4e w0, w1;
    w0.x = cvtpk(o[0], o[1]);  w0.y = cvtpk(o[2], o[3]);
    w0.z = cvtpk(o[4], o[5]);  w0.w = cvtpk(o[6], o[7]);
    w1.x = cvtpk(o[8], o[9]);  w1.y = cvtpk(o[10], o[11]);
    w1.z = cvtpk(o[12], o[13]); w1.w = cvtpk(o[14], o[15]);
    *(uint4e*)&sX[boff(r, d0)] = w0;
    *(uint4e*)&sX[boff(r, d0 + 8)] = w1;
  }
  if (t < E_) {
    sSrc[t] = eidx[(size_t)g * 2 * E_ + t];
    sDst[t] = eidx[(size_t)g * 2 * E_ + E_ + t];
    sWt[t] = ewt[(size_t)g * E_ + t];
    sEm[t] = (float)emsk[(size_t)g * E_ + t];
  } else if (t < 96) {
    sNm[t - 64] = (float)qmask[(size_t)g * N_ + (t - 64)];
  }
  syncb();

  // ---- A fragments (reused for all 8 E2 GEMMs) ----
  short8 aF[2][4];
#pragma unroll
  for (int c = 0; c < 2; ++c)
#pragma unroll
    for (int q = 0; q < 4; ++q)
      aF[c][q] = *(const short8*)&sX[boff(c * 16 + (lane & 15), q * 32 + ((lane >> 4) << 3))];

  // ---- ballot-based per-node masks (wave w owns nodes 8w..8w+7) ----
  {
    const int dl = sDst[lane];
    const float eml = sEm[lane];
    const int wtl = sWt[lane];
    const bool val = eml > 0.f;
    const u64 wt0m = __ballot(wtl == 0);
#pragma unroll
    for (int k = 0; k < 8; ++k) {
      const int n = wave * 8 + k;
      const u64 inc = __ballot(val && dl == n);
      if (lane == k) {
        sInc[n] = inc;
        const float cnt = (float)__popcll(inc);
        const float c0 = (float)__popcll(inc & wt0m);
        const float rinv = 1.f / fmaxf(cnt, 1.f);
        sC0[n] = c0 * rinv;
        sC1[n] = (cnt - c0) * rinv;
      }
    }
    if (wave == 3) {
      float nmv = (lane < 32) ? sNm[lane] : 0.f;
      float emv = eml;
#pragma unroll
      for (int m = 1; m < 64; m <<= 1) { nmv += __shfl_xor(nmv, m); emv += __shfl_xor(emv, m); }
      if (lane == 0) {
        sNmSum = nmv;
        sValid = (nmv > 0.f && emv > 0.f) ? 1.f : 0.f;
      }
    }
  }
  syncb();   // all aF reads of sX done -> safe to overwrite sX region with tables

  // ---- stage EW / att tables (f16) into the (now dead) sX region ----
  {
    const float* ewg = (const float*)(ws + EW_OFF);
    const f32x4 e4 = *(const f32x4*)&ewg[t << 2];
    uint2e p;
    p.x = pkrtz(e4[0], e4[1]);
    p.y = pkrtz(e4[2], e4[3]);
    *(uint2e*)&sEW[t << 2] = p;
    if (t < 128) {
      const f32x4 a4 = *(const f32x4*)&att[t << 2];
      uint2e q;
      q.x = pkrtz(a4[0], a4[1]);
      q.y = pkrtz(a4[2], a4[3]);
      *(uint2e*)&sAtt[t << 2] = q;
    }
  }

  const half2e pslope = {(_Float16)0.2f, (_Float16)0.2f};
  half2e accA[4] = {}, accB[4] = {};   // packed head-mean accum: node t>>3, d = (t&7)*16 + 2k(+1)

  for (int h = 0; h < H_; ++h) {
    // E2: xl / xr projections via MFMA -> f16 tiles, no activation
    gemm_e<true, false>(aF, wlp + h * 16384, bl + h * D_, 0.f, sXl, lane, wave);
    gemm_e<true, false>(aF, wrp + h * 16384, br + h * D_, 0.f, sXr, lane, wave);
    syncb();
    // E3: edge exp-logits (4 lanes/edge, packed f16 math + fdot2)
    {
      const int e = t >> 2, qu = t & 3;
      const int sn = sSrc[e], dn = sDst[e];
      const int ewb = (sWt[e] << 9) + (h << 7);
      float dx = 0.f, dy = 0.f;
#pragma unroll
      for (int ch = 0; ch < 4; ++ch) {
        const int dd = qu * 32 + ch * 8;
        const uint4e xlu = *(const uint4e*)&sXl[boff(sn, dd)];
        const uint4e xru = *(const uint4e*)&sXr[boff(dn, dd)];
        const uint4e ewu = *(const uint4e*)&sEW[ewb + dd];
        const uint4e atu = *(const uint4e*)&sAtt[(h << 7) + dd];
#pragma unroll
        for (int k = 0; k < 4; ++k) {
          half2e z = u2h(xlu[k]) + u2h(xru[k]) + u2h(ewu[k]);
          z = __builtin_elementwise_max(z, z * pslope);
          if (k & 1) dy = __builtin_amdgcn_fdot2(z, u2h(atu[k]), dy, false);
          else       dx = __builtin_amdgcn_fdot2(z, u2h(atu[k]), dx, false);
        }
      }
      float dot = dx + dy;
      dot += __shfl_xor(dot, 1);
      dot += __shfl_xor(dot, 2);
      const float ex = (sEm[e] > 0.f) ? __expf(dot) : 0.f;
      if (qu == 0) sExpE[e] = ex;
    }
    // E4: self-loop exp-logit (8 lanes/node, packed f16)
    {
      const int n = t >> 3, l8 = t & 7;
      const half2e c02 = {(_Float16)sC0[n], (_Float16)sC0[n]};
      const half2e c12 = {(_Float16)sC1[n], (_Float16)sC1[n]};
      float dx = 0.f, dy = 0.f;
#pragma unroll
      for (int ch = 0; ch < 2; ++ch) {
        const int dd = (l8 << 4) + ch * 8;
        const uint4e xlu = *(const uint4e*)&sXl[boff(n, dd)];
        const uint4e xru = *(const uint4e*)&sXr[boff(n, dd)];
        const uint4e e0u = *(const uint4e*)&sEW[(h << 7) + dd];
        const uint4e e1u = *(const uint4e*)&sEW[512 + (h << 7) + dd];
        const uint4e atu = *(const uint4e*)&sAtt[(h << 7) + dd];
#pragma unroll
        for (int k = 0; k < 4; ++k) {
          half2e lw = u2h(e0u[k]) * c02 + u2h(e1u[k]) * c12;
          half2e z = u2h(xlu[k]) + u2h(xru[k]) + lw;
          z = __builtin_elementwise_max(z, z * pslope);
          if (k & 1) dy = __builtin_amdgcn_fdot2(z, u2h(atu[k]), dy, false);
          else       dx = __builtin_amdgcn_fdot2(z, u2h(atu[k]), dx, false);
        }
      }
      float dot = dx + dy;
      dot += __shfl_xor(dot, 1);
      dot += __shfl_xor(dot, 2);
      dot += __shfl_xor(dot, 4);
      if (l8 == 0) sExpS[n] = __expf(dot);
    }
    syncb();
    // E6: den pass then packed-f16 aggregation directly into accA/accB
    {
      const int n = t >> 3, l8 = t & 7, db = l8 << 4;
      const float es = sExpS[n];
      const u64 mb = sInc[n];
      float den = es;
      u64 m2 = mb;
      while (m2) { const int e = __builtin_ctzll(m2); m2 &= m2 - 1; den += sExpE[e]; }
      const float rd = 0.25f / den;
      m2 = mb;
      while (m2) {
        const int e = __builtin_ctzll(m2); m2 &= m2 - 1;
        const _Float16 wh = (_Float16)(rd * sExpE[e]);
        const half2e w2 = {wh, wh};
        const int sn = sSrc[e];
        const uint4e a0 = *(const uint4e*)&sXl[boff(sn, db)];
        const uint4e a1 = *(const uint4e*)&sXl[boff(sn, db + 8)];
#pragma unroll
        for (int k = 0; k < 4; ++k) {
          accA[k] = u2h(a0[k]) * w2 + accA[k];
          accB[k] = u2h(a1[k]) * w2 + accB[k];
        }
      }
      const _Float16 wsh = (_Float16)(rd * es);
      const half2e ws2 = {wsh, wsh};
      const uint4e s0 = *(const uint4e*)&sXl[boff(n, db)];
      const uint4e s1 = *(const uint4e*)&sXl[boff(n, db + 8)];
#pragma unroll
      for (int k = 0; k < 4; ++k) {
        accA[k] = u2h(s0[k]) * ws2 + accA[k];
        accB[k] = u2h(s1[k]) * ws2 + accB[k];
      }
    }
    syncb();
  }

  // ---- gout = head-mean + gat_b -> bf16 A-matrix in sX (tables now dead) ----
  {
    const int n = t >> 3, l8 = t & 7, db = l8 << 4;
    const float4 g0 = *(const float4*)&gatb[db];
    const float4 g1 = *(const float4*)&gatb[db + 4];
    const float4 g2 = *(const float4*)&gatb[db + 8];
    const float4 g3 = *(const float4*)&gatb[db + 12];
    const float gv[16] = {g0.x, g0.y, g0.z, g0.w, g1.x, g1.y, g1.z, g1.w,
                          g2.x, g2.y, g2.z, g2.w, g3.x, g3.y, g3.z, g3.w};
    uint4e o0, o1;
    unsigned* po0 = (unsigned*)&o0;
    unsigned* po1 = (unsigned*)&o1;
#pragma unroll
    for (int k = 0; k < 4; ++k) {
      po0[k] = cvtpk((float)accA[k].x + gv[2 * k], (float)accA[k].y + gv[2 * k + 1]);
      po1[k] = cvtpk((float)accB[k].x + gv[8 + 2 * k], (float)accB[k].y + gv[8 + 2 * k + 1]);
    }
    *(uint4e*)&sX[boff(n, db)] = o0;
    *(uint4e*)&sX[boff(n, db + 8)] = o1;
  }
  syncb();

  // ---- FFN via MFMA (bf16 tiles) ----
  {
    short8 aG[2][4];
#pragma unroll
    for (int c = 0; c < 2; ++c)
#pragma unroll
      for (int q = 0; q < 4; ++q)
        aG[c][q] = *(const short8*)&sX[boff(c * 16 + (lane & 15), q * 32 + ((lane >> 4) << 3))];
    gemm_e<false, true>(aG, w1p, b1, 0.01f, sXl, lane, wave);
    syncb();
#pragma unroll
    for (int c = 0; c < 2; ++c)
#pragma unroll
      for (int q = 0; q < 4; ++q)
        aG[c][q] = *(const short8*)&sXl[boff(c * 16 + (lane & 15), q * 32 + ((lane >> 4) << 3))];
    gemm_e<false, false>(aG, w2p, b2, 0.f, sXr, lane, wave);
  }
  syncb();

  // ---- masked mean pool (sX region dead again -> sPool lives there) ----
  if (t < D_) {
    float acc = 0.f;
    for (int n = 0; n < N_; ++n) acc = fmaf(b2f(sXr[boff(n, t)]), sNm[n], acc);
    sPool[t] = acc * (1.f / fmaxf(sNmSum, 1.f)) * sValid;
  }
  syncb();
  // ---- LN2 + store ----
  if (t < 64) {
    const float v0 = sPool[t], v1 = sPool[t + 64];
    float s = v0 + v1, ss = v0 * v0 + v1 * v1;
#pragma unroll
    for (int m = 1; m < 64; m <<= 1) { s += __shfl_xor(s, m); ss += __shfl_xor(ss, m); }
    const float mu = s * (1.f / 128.f);
    const float inv = rsqrtf(ss * (1.f / 128.f) - mu * mu + 1e-5f);
    float* op = out + (size_t)g * D_;
    __builtin_nontemporal_store((v0 - mu) * inv * ln2g[t] + ln2b[t], op + t);
    __builtin_nontemporal_store((v1 - mu) * inv * ln2g[t + 64] + ln2b[t + 64], op + t + 64);
  }
}

extern "C" void kernel_launch(void* const* d_in, const int* in_sizes, int n_in,
                              void* d_out, int out_size, void* d_ws, size_t ws_size,
                              hipStream_t stream) {
  (void)in_sizes; (void)n_in; (void)out_size; (void)ws_size;
  const float* qe   = (const float*)d_in[0];
  const int*   qm   = (const int*)d_in[1];
  const int*   ei   = (const int*)d_in[2];
  const int*   ew   = (const int*)d_in[3];
  const int*   em   = (const int*)d_in[4];
  const float* ln1g = (const float*)d_in[5];
  const float* ln1b = (const float*)d_in[6];
  const float* embT = (const float*)d_in[7];
  const float* Wl   = (const float*)d_in[8];
  const float* bl   = (const float*)d_in[9];
  const float* Wr   = (const float*)d_in[10];
  const float* br   = (const float*)d_in[11];
  const float* We   = (const float*)d_in[12];
  const float* att  = (const float*)d_in[13];
  const float* gatb = (const float*)d_in[14];
  const float* W1   = (const float*)d_in[15];
  const float* b1   = (const float*)d_in[16];
  const float* W2   = (const float*)d_in[17];
  const float* b2   = (const float*)d_in[18];
  const float* ln2g = (const float*)d_in[19];
  const float* ln2b = (const float*)d_in[20];
  float* out = (float*)d_out;
  unsigned char* ws = (unsigned char*)d_ws;

  pack_weights<<<dim3(324), dim3(256), 0, stream>>>(Wl, Wr, W1, W2, embT, We, ws);
  gat_main<<<dim3(G_), dim3(256), 0, stream>>>(ws, qe, ln1g, ln1b, qm, ei, ew, em,
                                               bl, br, att, gatb, b1, b2, ln2g, ln2b, out);
}